// Round 1
// baseline (37.066 us; speedup 1.0000x reference)
//
#include <hip/hip_runtime.h>
#include <math.h>

static constexpr int B  = 4096;
static constexpr int L  = 4096;
static constexpr int NT = B * 64;          // 262144 power-series elements
static constexpr int RED_BLOCKS  = 256;
static constexpr int RED_THREADS = 256;

__device__ __constant__ float c_ps_powers[16] = {
    -5.0f, -4.0f, -3.0f, -2.0f, -1.5f, -1.0f, -0.5f, 0.0f,
     0.5f,  2.0f,  0.33333334f, 3.0f, 0.25f, 4.0f, 0.2f, 5.0f};

__device__ __constant__ float c_poly[5] = {2.0f, 5.0f, 8.0f, 11.0f, 14.0f};

// ---------------------------------------------------------------------------
// Kernel 1: per-block partial sum/sumsq of t = pp ** PS_POWERS  (double acc)
// part[0..255] = sum, part[256..511] = sumsq
// ---------------------------------------------------------------------------
__global__ __launch_bounds__(RED_THREADS)
void k_reduce_partial(const float* __restrict__ pp, double* __restrict__ part) {
    const int tid = threadIdx.x;
    const int gid = blockIdx.x * RED_THREADS + tid;
    double s = 0.0, s2 = 0.0;
    for (int i = gid; i < NT; i += RED_BLOCKS * RED_THREADS) {
        const int b = i >> 6;
        const int j = i & 63;
        const float x = pp[(b << 2) + (j >> 4)];
        const float t = powf(x, c_ps_powers[j & 15]);
        s  += (double)t;
        s2 += (double)t * (double)t;
    }
    __shared__ double sh_s[RED_THREADS];
    __shared__ double sh_s2[RED_THREADS];
    sh_s[tid] = s; sh_s2[tid] = s2;
    __syncthreads();
    for (int off = RED_THREADS >> 1; off > 0; off >>= 1) {
        if (tid < off) {
            sh_s[tid]  += sh_s[tid + off];
            sh_s2[tid] += sh_s2[tid + off];
        }
        __syncthreads();
    }
    if (tid == 0) {
        part[blockIdx.x]              = sh_s[0];
        part[RED_BLOCKS + blockIdx.x] = sh_s2[0];
    }
}

// ---------------------------------------------------------------------------
// Kernel 2: finalize mean and 1/std (unbiased, ddof=1)
// stats[0] = mean, stats[1] = inv_std
// ---------------------------------------------------------------------------
__global__ __launch_bounds__(RED_BLOCKS)
void k_finalize(const double* __restrict__ part, float* __restrict__ stats) {
    const int tid = threadIdx.x;
    __shared__ double sh_s[RED_BLOCKS];
    __shared__ double sh_s2[RED_BLOCKS];
    sh_s[tid]  = part[tid];
    sh_s2[tid] = part[RED_BLOCKS + tid];
    __syncthreads();
    for (int off = RED_BLOCKS >> 1; off > 0; off >>= 1) {
        if (tid < off) {
            sh_s[tid]  += sh_s[tid + off];
            sh_s2[tid] += sh_s2[tid + off];
        }
        __syncthreads();
    }
    if (tid == 0) {
        const double n    = (double)NT;
        const double mean = sh_s[0] / n;
        const double var  = (sh_s2[0] - n * mean * mean) / (n - 1.0);
        stats[0] = (float)mean;
        stats[1] = (float)(1.0 / sqrt(var));
    }
}

// ---------------------------------------------------------------------------
// Kernel 3: per row — recompute features, MLP -> 5 scaled coefficients,
// then stream eta row with float4, evaluating the derivative polynomial.
// dy = c0'*e + c1'*e^4 + c2'*e^7 + c3'*e^10 + c4'*e^13,  ck' = ck * p_k
// ---------------------------------------------------------------------------
__device__ __forceinline__ float poly_eval(float e, float c0, float c1,
                                           float c2, float c3, float c4) {
    const float e3 = e * e * e;
    float w   = e;             // e^1
    float acc = c0 * w;
    w *= e3;                   // e^4
    acc = fmaf(c1, w, acc);
    w *= e3;                   // e^7
    acc = fmaf(c2, w, acc);
    w *= e3;                   // e^10
    acc = fmaf(c3, w, acc);
    w *= e3;                   // e^13
    acc = fmaf(c4, w, acc);
    return acc;
}

__global__ __launch_bounds__(256)
void k_main(const float* __restrict__ pp,  const float* __restrict__ eta,
            const float* __restrict__ W1,  const float* __restrict__ b1,
            const float* __restrict__ W2,  const float* __restrict__ b2,
            const float* __restrict__ stats, float* __restrict__ out) {
    const int row = blockIdx.x;
    const int tid = threadIdx.x;

    __shared__ float sh_r[64];   // relu(norm)
    __shared__ float sh_h[32];   // hidden layer
    __shared__ float sh_c[5];    // scaled coefficients

    const float mean    = stats[0];
    const float inv_std = stats[1];

    if (tid < 64) {
        const float x = pp[(row << 2) + (tid >> 4)];
        const float t = powf(x, c_ps_powers[tid & 15]);
        sh_r[tid] = fmaxf((t - mean) * inv_std, 0.0f);
    }
    __syncthreads();

    if (tid < 32) {
        float acc = b1[tid];
        const float* w = W1 + tid * 64;
        #pragma unroll
        for (int j = 0; j < 64; ++j) acc = fmaf(sh_r[j], w[j], acc);
        sh_h[tid] = acc;
    }
    __syncthreads();

    if (tid < 5) {
        float acc = b2[tid];
        const float* w = W2 + tid * 32;
        #pragma unroll
        for (int o = 0; o < 32; ++o) acc = fmaf(sh_h[o], w[o], acc);
        sh_c[tid] = acc * c_poly[tid];
    }
    __syncthreads();

    const float c0 = sh_c[0], c1 = sh_c[1], c2 = sh_c[2],
                c3 = sh_c[3], c4 = sh_c[4];

    const float4* ep = reinterpret_cast<const float4*>(eta + (size_t)row * L);
    float4*       op = reinterpret_cast<float4*>(out + (size_t)row * L);

    #pragma unroll
    for (int i = tid; i < L / 4; i += 256) {
        const float4 e = ep[i];
        float4 r;
        r.x = poly_eval(e.x, c0, c1, c2, c3, c4);
        r.y = poly_eval(e.y, c0, c1, c2, c3, c4);
        r.z = poly_eval(e.z, c0, c1, c2, c3, c4);
        r.w = poly_eval(e.w, c0, c1, c2, c3, c4);
        op[i] = r;
    }
}

// ---------------------------------------------------------------------------
extern "C" void kernel_launch(void* const* d_in, const int* in_sizes, int n_in,
                              void* d_out, int out_size, void* d_ws, size_t ws_size,
                              hipStream_t stream) {
    const float* pp  = (const float*)d_in[0];   // [B,4]
    const float* eta = (const float*)d_in[1];   // [B,L]
    const float* W1  = (const float*)d_in[2];   // [32,64]
    const float* b1  = (const float*)d_in[3];   // [32]
    const float* W2  = (const float*)d_in[4];   // [5,32]
    const float* b2  = (const float*)d_in[5];   // [5]
    float* out = (float*)d_out;

    double* part = (double*)d_ws;                        // 512 doubles
    float*  stats = (float*)(part + 2 * RED_BLOCKS);     // 2 floats

    k_reduce_partial<<<RED_BLOCKS, RED_THREADS, 0, stream>>>(pp, part);
    k_finalize<<<1, RED_BLOCKS, 0, stream>>>(part, stats);
    k_main<<<B, 256, 0, stream>>>(pp, eta, W1, b1, W2, b2, stats, out);
}